// Round 3
// baseline (906.839 us; speedup 1.0000x reference)
//
#include <hip/hip_runtime.h>
#include <hip/hip_bf16.h>
#include <cstdint>
#include <cstddef>

// Problem shape (fixed by reference): B=8, N=1024, D=768, H=12, dh=64, 3 branches
#define B_   8
#define N_   1024
#define D_   768
#define H_   12
#define DH_  64
#define M_   (B_ * N_)          // 8192 rows
#define WSZ_ (D_ * D_)          // 589824 per weight matrix

typedef __bf16 bf16;
typedef bf16  bf16x8  __attribute__((ext_vector_type(8)));
typedef bf16  bf16x4  __attribute__((ext_vector_type(4)));
typedef float floatx4 __attribute__((ext_vector_type(4)));

// ---------------------------------------------------------------------------
// async global->LDS, 16B per lane (wave-uniform LDS base + lane*16)
__device__ __forceinline__ void gload_lds16(const void* g, void* l) {
    __builtin_amdgcn_global_load_lds(
        (const __attribute__((address_space(1))) unsigned int*)g,
        (__attribute__((address_space(3))) unsigned int*)l, 16, 0, 0);
}

// ---------------------------------------------------------------------------
// Kernel 1: per-row norm -> branch scales; x -> bf16.
__global__ __launch_bounds__(256) void prep_x(const float* __restrict__ x,
                                              bf16* __restrict__ xbf,
                                              float* __restrict__ sc /* [2][M_] */) {
    int row = blockIdx.x;
    int tid = threadIdx.x;
    const float* xr = x + (size_t)row * D_;
    bf16* xo = xbf + (size_t)row * D_;
    float v0 = xr[tid], v1 = xr[tid + 256], v2 = xr[tid + 512];
    xo[tid]       = (bf16)v0;
    xo[tid + 256] = (bf16)v1;
    xo[tid + 512] = (bf16)v2;
    float ss = v0 * v0 + v1 * v1 + v2 * v2;
    for (int off = 32; off; off >>= 1) ss += __shfl_xor(ss, off, 64);
    __shared__ float red[4];
    if ((tid & 63) == 0) red[tid >> 6] = ss;
    __syncthreads();
    if (tid == 0) {
        float t2 = red[0] + red[1] + red[2] + red[3];
        float t  = sqrtf(t2);                       // true ||x||
        const float scst = 0.31622776601683794f;    // sqrt(0.1)
        float un = fmaxf(t, 1e-5f);
        float s1 = tanhf(scst * un) / (scst * un);  // expmap0 scale
        float nh = fmaxf(t * s1, 1e-5f);            // project
        float maxnorm = (1.0f - 4e-3f) / scst;
        float sh = (nh > maxnorm) ? s1 * (maxnorm / nh) : s1;
        float arg = fminf(scst * un, 1.0f - 1e-5f); // logmap0 scale
        float artanh = 0.5f * logf((1.0f + arg) / (1.0f - arg));
        float ssc = artanh / (un * scst);
        sc[row]      = sh;
        sc[M_ + row] = ssc;
    }
}

// ---------------------------------------------------------------------------
// Kernel 2: weights fp32 -> bf16, layout wbf[branch][t][o][k], t: 0=q,1=k,2=v
__global__ __launch_bounds__(256) void prep_w(const float* __restrict__ wq,
                                              const float* __restrict__ wk,
                                              const float* __restrict__ wv,
                                              bf16* __restrict__ wbf) {
    size_t i = ((size_t)blockIdx.x * 256 + threadIdx.x) * 4;  // 9*WSZ_ total
    int z = (int)(i / WSZ_);
    int r = (int)(i % WSZ_);
    int branch = z / 3, t = z % 3;
    const float* src = (t == 0 ? wq : t == 1 ? wk : wv) + (size_t)branch * WSZ_ + r;
    float4 f = *(const float4*)src;
    bf16x4 o = { (bf16)f.x, (bf16)f.y, (bf16)f.z, (bf16)f.w };
    *(bf16x4*)(wbf + i) = o;
}

// ---------------------------------------------------------------------------
// Kernel 3: Y = x @ W^T, epilogue y = (s_branch[row]*y + bias[col]) * qscale
// q (t==0) additionally scaled by log2(e) so attention softmax can use exp2.
#define BM 128
#define BN 128
#define BK 32
__global__ __launch_bounds__(256) void gemm_qkv(
        const bf16* __restrict__ xbf, const bf16* __restrict__ wbf_all,
        const float* __restrict__ bq, const float* __restrict__ bk,
        const float* __restrict__ bv, const float* __restrict__ sc,
        int branch, bf16* __restrict__ qkv) {
    int t = blockIdx.z;
    const bf16*  wsrc = wbf_all + (size_t)(branch * 3 + t) * WSZ_;
    const float* bias = (t == 0 ? bq : t == 1 ? bk : bv) + branch * D_;
    bf16* out = qkv + (size_t)t * M_ * D_;
    int bm0 = blockIdx.y * BM;
    int bn0 = blockIdx.x * BN;

    __shared__ bf16 lA[BM * BK];   // 8 KB
    __shared__ bf16 lB[BN * BK];   // 8 KB

    int tid = threadIdx.x;
    int w = tid >> 6, lane = tid & 63;
    int wr = w >> 1, wc = w & 1;
    int quad = lane >> 4, c15 = lane & 15;
    int lrow = lane >> 2;           // 0..15 within a 16-row chunk
    int lcol = (lane & 3) * 8;      // k offset 0/8/16/24

    floatx4 acc[4][4];
    for (int i = 0; i < 4; i++)
        for (int j = 0; j < 4; j++)
            acc[i][j] = (floatx4){0.f, 0.f, 0.f, 0.f};

    for (int k0 = 0; k0 < D_; k0 += BK) {
        const bf16* ga = xbf  + ((size_t)(bm0 + w * 32 + lrow) * D_ + k0 + lcol);
        const bf16* gb = wsrc + ((size_t)(bn0 + w * 32 + lrow) * D_ + k0 + lcol);
        gload_lds16(ga,           (char*)lA + w * 2048);
        gload_lds16(ga + 16 * D_, (char*)lA + w * 2048 + 1024);
        gload_lds16(gb,           (char*)lB + w * 2048);
        gload_lds16(gb + 16 * D_, (char*)lB + w * 2048 + 1024);
        __syncthreads();

        int arow = wr * 64 + c15;
        int brow = wc * 64 + c15;
        int kq = quad * 8;
        bf16x8 af[4], bfm[4];
        for (int i = 0; i < 4; i++) af[i]  = *(const bf16x8*)(lA + (arow + i * 16) * BK + kq);
        for (int j = 0; j < 4; j++) bfm[j] = *(const bf16x8*)(lB + (brow + j * 16) * BK + kq);
        for (int i = 0; i < 4; i++)
            for (int j = 0; j < 4; j++)
                acc[i][j] = __builtin_amdgcn_mfma_f32_16x16x32_bf16(af[i], bfm[j], acc[i][j], 0, 0, 0);
        __syncthreads();
    }

    // epilogue: y = (s[row]*y + bias[col]) * qs
    const float* scb = (branch == 0) ? nullptr : sc + (size_t)(branch - 1) * M_;
    float qs = (t == 0) ? 1.4426950408889634f : 1.0f;   // log2(e) folded into q
    float bj[4];
    for (int j = 0; j < 4; j++) bj[j] = bias[bn0 + wc * 64 + j * 16 + c15];
    for (int i = 0; i < 4; i++) {
        int gRow0 = bm0 + wr * 64 + i * 16 + quad * 4;
        for (int r = 0; r < 4; r++) {
            float s = scb ? scb[gRow0 + r] : 1.0f;
            bf16* orow = out + (size_t)(gRow0 + r) * D_;
            for (int j = 0; j < 4; j++) {
                int gCol = bn0 + wc * 64 + j * 16 + c15;
                orow[gCol] = (bf16)((s * acc[i][j][r] + bj[j]) * qs);
            }
        }
    }
}

// ---------------------------------------------------------------------------
// Kernel 4: flash attention, 64 q-rows/block (5 blocks/CU), no-max exp2
// softmax, register-prefetched K/V staging, XCD-local K/V reuse via grid
// layout (bh on x: the 16 q-tiles of one (batch,head) share an XCD's L2).
#define LDK 74   // 37 words == 5 (mod 32): <=2-way LDS bank aliasing (free)
__global__ __launch_bounds__(256) void attn(const bf16* __restrict__ qkv,
                                            float* __restrict__ out,
                                            int accumulate) {
    int bh = blockIdx.x;              // 0..95  (same-bh blocks -> same XCD)
    int qt = blockIdx.y;              // 0..15
    int batch = bh / H_, head = bh % H_;
    int n0 = qt * 64;
    int tid = threadIdx.x, w = tid >> 6, lane = tid & 63;
    int quad = lane >> 4, c15 = lane & 15;

    const bf16* qb = qkv;
    const bf16* kb = qkv + (size_t)M_ * D_;
    const bf16* vb = qkv + (size_t)2 * M_ * D_;
    size_t baseRow = (size_t)batch * N_;
    int colOff = head * DH_;

    __shared__ bf16 sK[64 * LDK];        // K tile [key][d]            9472 B
    __shared__ bf16 sVt[64 * LDK];       // V tile transposed [d][key] 9472 B
    __shared__ bf16 sP[4][16 * LDK];     // per-wave P [q][key]        9472 B

    // Q A-fragments, held in registers for the whole block
    bf16x8 aq0, aq1;
    {
        const bf16* qp = qb + ((baseRow + n0 + w * 16 + c15) * D_ + colOff + quad * 8);
        aq0 = *(const bf16x8*)qp;
        aq1 = *(const bf16x8*)(qp + 32);
    }

    float lsum[4];
    floatx4 o_acc[4];
    for (int r = 0; r < 4; r++) lsum[r] = 0.f;
    for (int j = 0; j < 4; j++) o_acc[j] = (floatx4){0.f, 0.f, 0.f, 0.f};

    // staging assignments (fixed per thread)
    int kkey = tid >> 3;                 // 0..31 (K rows; +32 for 2nd chunk)
    int kcol = (tid & 7) << 3;
    int vkey = tid >> 2;                 // 0..63 (V rows)
    int vd0  = (tid & 3) << 4;           // d block 0/16/32/48
    int kodd = vkey & 1;
    int keyLow = vkey & ~1;

    // prologue: prefetch tile 0 into registers
    bf16x8 kr0, kr1, vr0, vr1;
    {
        const bf16* kp = kb + (baseRow + kkey) * D_ + colOff + kcol;
        kr0 = *(const bf16x8*)kp;
        kr1 = *(const bf16x8*)(kp + 32 * D_);
        const bf16* vp = vb + (baseRow + vkey) * D_ + colOff + vd0;
        vr0 = *(const bf16x8*)vp;
        vr1 = *(const bf16x8*)(vp + 8);
    }

    for (int kt = 0; kt < 16; kt++) {
        // --- write current tile (registers) into LDS ---
        *(bf16x8*)(sK + kkey * LDK + kcol)        = kr0;
        *(bf16x8*)(sK + (kkey + 32) * LDK + kcol) = kr1;
        {   // V transpose via pair-exchange (4 shfl + 8 conflict-free b32)
            union { bf16x8 v; uint32_t d[4]; } u0, u1;
            u0.v = vr0; u1.v = vr1;
            uint32_t recv[4];
            #pragma unroll
            for (int t = 0; t < 4; t++) {
                uint32_t send = kodd ? u0.d[t] : u1.d[t];
                recv[t] = __shfl_xor((int)send, 4, 64);
            }
            uint32_t mine[4];
            for (int t = 0; t < 4; t++) mine[t] = kodd ? u1.d[t] : u0.d[t];
            int rowbase = vd0 + (kodd ? 8 : 0);
            #pragma unroll
            for (int i = 0; i < 8; i++) {
                uint32_t m16 = (mine[i >> 1] >> ((i & 1) * 16)) & 0xffffu;
                uint32_t p16 = (recv[i >> 1] >> ((i & 1) * 16)) & 0xffffu;
                uint32_t word = kodd ? ((m16 << 16) | p16) : ((p16 << 16) | m16);
                *(uint32_t*)((char*)sVt + (size_t)(rowbase + i) * (LDK * 2) + keyLow * 2) = word;
            }
        }
        __syncthreads();

        // --- prefetch next tile into registers (consumed next iteration) ---
        {
            int nt = (kt + 1) & 15;      // wraps to a valid tile; last iter's
            size_t tb = baseRow + nt * 64;               // loads are unused
            const bf16* kp = kb + (tb + kkey) * D_ + colOff + kcol;
            kr0 = *(const bf16x8*)kp;
            kr1 = *(const bf16x8*)(kp + 32 * D_);
            const bf16* vp = vb + (tb + vkey) * D_ + colOff + vd0;
            vr0 = *(const bf16x8*)vp;
            vr1 = *(const bf16x8*)(vp + 8);
        }

        // --- S = Q K^T + no-max softmax, P -> wave-private LDS ---
        for (int j = 0; j < 4; j++) {
            const bf16* kp = sK + (j * 16 + c15) * LDK + quad * 8;
            bf16x8 b0 = *(const bf16x8*)kp;
            bf16x8 b1 = *(const bf16x8*)(kp + 32);
            floatx4 z = (floatx4){0.f, 0.f, 0.f, 0.f};
            z = __builtin_amdgcn_mfma_f32_16x16x32_bf16(aq0, b0, z, 0, 0, 0);
            z = __builtin_amdgcn_mfma_f32_16x16x32_bf16(aq1, b1, z, 0, 0, 0);
            #pragma unroll
            for (int r = 0; r < 4; r++) {
                float p = exp2f(fminf(z[r], 120.f));   // q pre-scaled by log2e
                lsum[r] += p;
                sP[w][(quad * 4 + r) * LDK + j * 16 + c15] = (bf16)p;
            }
        }

        // --- O += P V  (A = P rows, B = V^T rows; wave-private, no barrier)
        bf16x8 ap0, ap1;
        {
            const bf16* pp = &sP[w][c15 * LDK + quad * 8];
            ap0 = *(const bf16x8*)pp;
            ap1 = *(const bf16x8*)(pp + 32);
        }
        for (int j = 0; j < 4; j++) {
            const bf16* vtp = sVt + (j * 16 + c15) * LDK + quad * 8;
            bf16x8 bv0 = *(const bf16x8*)vtp;
            bf16x8 bv1 = *(const bf16x8*)(vtp + 32);
            o_acc[j] = __builtin_amdgcn_mfma_f32_16x16x32_bf16(ap0, bv0, o_acc[j], 0, 0, 0);
            o_acc[j] = __builtin_amdgcn_mfma_f32_16x16x32_bf16(ap1, bv1, o_acc[j], 0, 0, 0);
        }
        __syncthreads();
    }

    // --- final l reduction (once per block) + epilogue ---
    for (int r = 0; r < 4; r++) {
        float s = lsum[r];
        s += __shfl_xor(s, 1, 64);
        s += __shfl_xor(s, 2, 64);
        s += __shfl_xor(s, 4, 64);
        s += __shfl_xor(s, 8, 64);
        lsum[r] = 1.0f / s;
    }
    for (int r = 0; r < 4; r++) {
        int row = n0 + w * 16 + quad * 4 + r;
        float* op = out + ((size_t)batch * N_ + row) * D_ + colOff;
        float inv = lsum[r];
        for (int j = 0; j < 4; j++) {
            float v = o_acc[j][r] * inv;
            int col = j * 16 + c15;
            if (accumulate) op[col] += v;
            else            op[col] = v;
        }
    }
}

// ---------------------------------------------------------------------------
extern "C" void kernel_launch(void* const* d_in, const int* in_sizes, int n_in,
                              void* d_out, int out_size, void* d_ws, size_t ws_size,
                              hipStream_t stream) {
    const float* x  = (const float*)d_in[0];
    const float* wq = (const float*)d_in[1];
    const float* bq = (const float*)d_in[2];
    const float* wk = (const float*)d_in[3];
    const float* bk = (const float*)d_in[4];
    const float* wv = (const float*)d_in[5];
    const float* bv = (const float*)d_in[6];
    float* out = (float*)d_out;

    // workspace layout (~61 MB total)
    char* ws = (char*)d_ws;
    bf16*  xbf = (bf16*)ws;                                   // 12,582,912 B
    bf16*  wbf = (bf16*)(ws + 12582912);                      // 10,616,832 B
    float* sc  = (float*)(ws + 12582912 + 10616832);          //     65,536 B
    bf16*  qkv = (bf16*)(ws + 12582912 + 10616832 + 65536);   // 37,748,736 B (one branch's q,k,v)

    hipLaunchKernelGGL(prep_x, dim3(M_), dim3(256), 0, stream, x, xbf, sc);
    hipLaunchKernelGGL(prep_w, dim3((9 * WSZ_ / 4) / 256), dim3(256), 0, stream, wq, wk, wv, wbf);
    for (int br = 0; br < 3; br++) {
        hipLaunchKernelGGL(gemm_qkv, dim3(D_ / BN, M_ / BM, 3), dim3(256), 0, stream,
                           xbf, wbf, bq, bk, bv, sc, br, qkv);
        hipLaunchKernelGGL(attn, dim3(B_ * H_, N_ / 64), dim3(256), 0, stream,
                           qkv, out, br);
    }
}

// Round 4
// 695.609 us; speedup vs baseline: 1.3037x; 1.3037x over previous
//
#include <hip/hip_runtime.h>
#include <hip/hip_bf16.h>
#include <cstdint>
#include <cstddef>

// Problem shape (fixed by reference): B=8, N=1024, D=768, H=12, dh=64, 3 branches
#define B_   8
#define N_   1024
#define D_   768
#define H_   12
#define DH_  64
#define M_   (B_ * N_)          // 8192 rows
#define WSZ_ (D_ * D_)          // 589824 per weight matrix

typedef __bf16 bf16;
typedef bf16  bf16x8  __attribute__((ext_vector_type(8)));
typedef bf16  bf16x4  __attribute__((ext_vector_type(4)));
typedef float floatx4 __attribute__((ext_vector_type(4)));

// ---------------------------------------------------------------------------
// async global->LDS, 16B per lane (wave-uniform LDS base + lane*16)
__device__ __forceinline__ void gload_lds16(const void* g, void* l) {
    __builtin_amdgcn_global_load_lds(
        (const __attribute__((address_space(1))) unsigned int*)g,
        (__attribute__((address_space(3))) unsigned int*)l, 16, 0, 0);
}

// ---------------------------------------------------------------------------
// Kernel 1: per-row norm -> branch scales; x -> bf16.
__global__ __launch_bounds__(256) void prep_x(const float* __restrict__ x,
                                              bf16* __restrict__ xbf,
                                              float* __restrict__ sc /* [2][M_] */) {
    int row = blockIdx.x;
    int tid = threadIdx.x;
    const float* xr = x + (size_t)row * D_;
    bf16* xo = xbf + (size_t)row * D_;
    float v0 = xr[tid], v1 = xr[tid + 256], v2 = xr[tid + 512];
    xo[tid]       = (bf16)v0;
    xo[tid + 256] = (bf16)v1;
    xo[tid + 512] = (bf16)v2;
    float ss = v0 * v0 + v1 * v1 + v2 * v2;
    for (int off = 32; off; off >>= 1) ss += __shfl_xor(ss, off, 64);
    __shared__ float red[4];
    if ((tid & 63) == 0) red[tid >> 6] = ss;
    __syncthreads();
    if (tid == 0) {
        float t2 = red[0] + red[1] + red[2] + red[3];
        float t  = sqrtf(t2);                       // true ||x||
        const float scst = 0.31622776601683794f;    // sqrt(0.1)
        float un = fmaxf(t, 1e-5f);
        float s1 = tanhf(scst * un) / (scst * un);  // expmap0 scale
        float nh = fmaxf(t * s1, 1e-5f);            // project
        float maxnorm = (1.0f - 4e-3f) / scst;
        float sh = (nh > maxnorm) ? s1 * (maxnorm / nh) : s1;
        float arg = fminf(scst * un, 1.0f - 1e-5f); // logmap0 scale
        float artanh = 0.5f * logf((1.0f + arg) / (1.0f - arg));
        float ssc = artanh / (un * scst);
        sc[row]      = sh;
        sc[M_ + row] = ssc;
    }
}

// ---------------------------------------------------------------------------
// Kernel 2: weights fp32 -> bf16, layout wbf[branch][t][o][k], t: 0=q,1=k,2=v
__global__ __launch_bounds__(256) void prep_w(const float* __restrict__ wq,
                                              const float* __restrict__ wk,
                                              const float* __restrict__ wv,
                                              bf16* __restrict__ wbf) {
    size_t i = ((size_t)blockIdx.x * 256 + threadIdx.x) * 4;  // 9*WSZ_ total
    int z = (int)(i / WSZ_);
    int r = (int)(i % WSZ_);
    int branch = z / 3, t = z % 3;
    const float* src = (t == 0 ? wq : t == 1 ? wk : wv) + (size_t)branch * WSZ_ + r;
    float4 f = *(const float4*)src;
    bf16x4 o = { (bf16)f.x, (bf16)f.y, (bf16)f.z, (bf16)f.w };
    *(bf16x4*)(wbf + i) = o;
}

// ---------------------------------------------------------------------------
// Kernel 3: Y = x @ W^T, epilogue y = (s_branch[row]*y + bias[col]) * qscale
// q (t==0) additionally scaled by log2(e) so attention softmax can use exp2.
#define BM 128
#define BN 128
#define BK 32
__global__ __launch_bounds__(256) void gemm_qkv(
        const bf16* __restrict__ xbf, const bf16* __restrict__ wbf_all,
        const float* __restrict__ bq, const float* __restrict__ bk,
        const float* __restrict__ bv, const float* __restrict__ sc,
        int branch, bf16* __restrict__ qkv) {
    int t = blockIdx.z;
    const bf16*  wsrc = wbf_all + (size_t)(branch * 3 + t) * WSZ_;
    const float* bias = (t == 0 ? bq : t == 1 ? bk : bv) + branch * D_;
    bf16* out = qkv + (size_t)t * M_ * D_;
    int bm0 = blockIdx.y * BM;
    int bn0 = blockIdx.x * BN;

    __shared__ bf16 lA[BM * BK];   // 8 KB
    __shared__ bf16 lB[BN * BK];   // 8 KB

    int tid = threadIdx.x;
    int w = tid >> 6, lane = tid & 63;
    int wr = w >> 1, wc = w & 1;
    int quad = lane >> 4, c15 = lane & 15;
    int lrow = lane >> 2;           // 0..15 within a 16-row chunk
    int lcol = (lane & 3) * 8;      // k offset 0/8/16/24

    floatx4 acc[4][4];
    for (int i = 0; i < 4; i++)
        for (int j = 0; j < 4; j++)
            acc[i][j] = (floatx4){0.f, 0.f, 0.f, 0.f};

    for (int k0 = 0; k0 < D_; k0 += BK) {
        const bf16* ga = xbf  + ((size_t)(bm0 + w * 32 + lrow) * D_ + k0 + lcol);
        const bf16* gb = wsrc + ((size_t)(bn0 + w * 32 + lrow) * D_ + k0 + lcol);
        gload_lds16(ga,           (char*)lA + w * 2048);
        gload_lds16(ga + 16 * D_, (char*)lA + w * 2048 + 1024);
        gload_lds16(gb,           (char*)lB + w * 2048);
        gload_lds16(gb + 16 * D_, (char*)lB + w * 2048 + 1024);
        __syncthreads();

        int arow = wr * 64 + c15;
        int brow = wc * 64 + c15;
        int kq = quad * 8;
        bf16x8 af[4], bfm[4];
        for (int i = 0; i < 4; i++) af[i]  = *(const bf16x8*)(lA + (arow + i * 16) * BK + kq);
        for (int j = 0; j < 4; j++) bfm[j] = *(const bf16x8*)(lB + (brow + j * 16) * BK + kq);
        for (int i = 0; i < 4; i++)
            for (int j = 0; j < 4; j++)
                acc[i][j] = __builtin_amdgcn_mfma_f32_16x16x32_bf16(af[i], bfm[j], acc[i][j], 0, 0, 0);
        __syncthreads();
    }

    // epilogue: y = (s[row]*y + bias[col]) * qs
    const float* scb = (branch == 0) ? nullptr : sc + (size_t)(branch - 1) * M_;
    float qs = (t == 0) ? 1.4426950408889634f : 1.0f;   // log2(e) folded into q
    float bj[4];
    for (int j = 0; j < 4; j++) bj[j] = bias[bn0 + wc * 64 + j * 16 + c15];
    for (int i = 0; i < 4; i++) {
        int gRow0 = bm0 + wr * 64 + i * 16 + quad * 4;
        for (int r = 0; r < 4; r++) {
            float s = scb ? scb[gRow0 + r] : 1.0f;
            bf16* orow = out + (size_t)(gRow0 + r) * D_;
            for (int j = 0; j < 4; j++) {
                int gCol = bn0 + wc * 64 + j * 16 + c15;
                orow[gCol] = (bf16)((s * acc[i][j][r] + bj[j]) * qs);
            }
        }
    }
}

// ---------------------------------------------------------------------------
// Kernel 4: transposed-S flash attention.
//   S^T = K·Q^T via mfma(A=K-frag, B=Q-frag): K loads straight from global
//   into A-operand layout (no sK LDS at all). Lane (c15,quad) then holds
//   P[key=16j+4*quad+r][q=c15] for frags j=0..3.
//   P must re-enter PV as B-operand B[q=c15][key=32w+8*quad+t]; the exchange
//   is done through a tiny per-wave LDS array sPX[w][u][destLane]:
//     writer (c15,quadS), frag j, pair (r0r1 / r2r3):
//       destQuad = 2*(j&1) + (quadS>>1); u = 2*(quadS&1) + {0,1}
//     reader (c15,q hat=quad) slot u holds keys 32w+8*quad+{2u,2u+1}.  Bank =
//     (u*64+L)%32 = L%32 -> <=2-way everywhere (free).
//   V transposed into sVt[d][key] (stride LDV=72: rows 144 B, 16B-aligned so
//   b128 reads stay b128) by key-pair packing: lane owns keys {2kp,2kp+1},
//   d-block db*8..+7; writes u32 (key-pair) words; bank = (4*(8db+i)+kp)%32
//   -> kp spans 0..31 -> <=2-way (free). No shuffles.
#define LDV 72
__global__ __launch_bounds__(256) void attn(const bf16* __restrict__ qkv,
                                            float* __restrict__ out,
                                            int accumulate) {
    int qt = blockIdx.x;              // 0..15
    int bh = blockIdx.y;              // 0..95
    int batch = bh / H_, head = bh % H_;
    int n0 = qt * 64;
    int tid = threadIdx.x, w = tid >> 6, lane = tid & 63;
    int quad = lane >> 4, c15 = lane & 15;

    const bf16* qb = qkv;
    const bf16* kb = qkv + (size_t)M_ * D_;
    const bf16* vb = qkv + (size_t)2 * M_ * D_;
    size_t baseRow = (size_t)batch * N_;
    int colOff = head * DH_;

    __shared__ bf16 sVt[64 * LDV];            // 9216 B
    __shared__ uint32_t sPX[4][2][4][64];     // 8192 B (per-wave private)

    // Q as B-operand frags (16 q-rows per wave), registers for whole kernel
    bf16x8 bq0, bq1;
    {
        const bf16* qp = qb + ((baseRow + n0 + w * 16 + c15) * D_ + colOff + quad * 8);
        bq0 = *(const bf16x8*)qp;
        bq1 = *(const bf16x8*)(qp + 32);
    }

    float lsum = 0.f;                 // in-lane: this lane's 16 keys per iter
    floatx4 o_acc[4];
    for (int j = 0; j < 4; j++) o_acc[j] = (floatx4){0.f, 0.f, 0.f, 0.f};

    // V staging assignment: key-pair kp, d-block db (8 d's)
    int kp = lane & 31;
    int db = 2 * w + (lane >> 5);
    const bf16* vptr = vb + (baseRow + 2 * kp) * D_ + colOff + db * 8;
    // K A-operand base: row c15 (+16j +64kt), col quad*8
    const bf16* kAbase = kb + (baseRow + c15) * D_ + colOff + quad * 8;

    for (int kt = 0; kt < 16; kt++) {
        // --- K frags: global -> VGPR in A-operand layout (8 x b128) ---
        bf16x8 kA[4][2];
        #pragma unroll
        for (int j = 0; j < 4; j++) {
            const bf16* kpp = kAbase + (size_t)(kt * 64 + 16 * j) * D_;
            kA[j][0] = *(const bf16x8*)kpp;
            kA[j][1] = *(const bf16x8*)(kpp + 32);
        }

        // --- stage V transposed: key-pair packed u32 writes, conflict-free ---
        {
            union { bf16x8 v; uint16_t h[8]; } ua, ub;
            ua.v = *(const bf16x8*)vptr;        // V[2kp][db*8 .. +7]
            ub.v = *(const bf16x8*)(vptr + D_); // V[2kp+1][...]
            #pragma unroll
            for (int i = 0; i < 8; i++) {
                uint32_t wd = (uint32_t)ua.h[i] | ((uint32_t)ub.h[i] << 16);
                *(uint32_t*)((char*)sVt + (size_t)((db * 8 + i) * LDV + 2 * kp) * 2) = wd;
            }
        }
        __syncthreads();

        // --- S^T = K Q^T, no-max exp2 softmax, pack P pairs ---
        uint32_t pw[4][2];
        #pragma unroll
        for (int j = 0; j < 4; j++) {
            floatx4 z = (floatx4){0.f, 0.f, 0.f, 0.f};
            z = __builtin_amdgcn_mfma_f32_16x16x32_bf16(kA[j][0], bq0, z, 0, 0, 0);
            z = __builtin_amdgcn_mfma_f32_16x16x32_bf16(kA[j][1], bq1, z, 0, 0, 0);
            union { bf16 b[2]; uint32_t u; } p01, p23;
            float e0 = __builtin_amdgcn_exp2f(fminf(z[0], 120.f));
            float e1 = __builtin_amdgcn_exp2f(fminf(z[1], 120.f));
            float e2 = __builtin_amdgcn_exp2f(fminf(z[2], 120.f));
            float e3 = __builtin_amdgcn_exp2f(fminf(z[3], 120.f));
            lsum += (e0 + e1) + (e2 + e3);
            p01.b[0] = (bf16)e0; p01.b[1] = (bf16)e1;
            p23.b[0] = (bf16)e2; p23.b[1] = (bf16)e3;
            pw[j][0] = p01.u;
            pw[j][1] = p23.u;
        }
        // scatter P pairs to the exchange array (wave-private, no barrier)
        {
            int u0 = (quad & 1) * 2;
            #pragma unroll
            for (int j = 0; j < 4; j++) {
                int L = (2 * (j & 1) + (quad >> 1)) * 16 + c15;
                sPX[w][j >> 1][u0][L]     = pw[j][0];
                sPX[w][j >> 1][u0 + 1][L] = pw[j][1];
            }
        }
        // gather B-operand P frags (keys 32w2+8*quad+t at lane c15)
        union { uint32_t g[4]; bf16x8 v; } pf0, pf1;
        #pragma unroll
        for (int u = 0; u < 4; u++) pf0.g[u] = sPX[w][0][u][lane];
        #pragma unroll
        for (int u = 0; u < 4; u++) pf1.g[u] = sPX[w][1][u][lane];

        // --- O^T += V^T P^T : mfma(A=Vt-frag, B=P-frag) ---
        #pragma unroll
        for (int jd = 0; jd < 4; jd++) {
            const bf16* vt = sVt + (16 * jd + c15) * LDV + quad * 8;
            bf16x8 a0 = *(const bf16x8*)vt;
            bf16x8 a1 = *(const bf16x8*)(vt + 32);
            o_acc[jd] = __builtin_amdgcn_mfma_f32_16x16x32_bf16(a0, pf0.v, o_acc[jd], 0, 0, 0);
            o_acc[jd] = __builtin_amdgcn_mfma_f32_16x16x32_bf16(a1, pf1.v, o_acc[jd], 0, 0, 0);
        }
        __syncthreads();

        vptr += (size_t)64 * D_;
    }

    // --- final l reduction across quads (disjoint key ranges) ---
    lsum += __shfl_xor(lsum, 16, 64);
    lsum += __shfl_xor(lsum, 32, 64);
    float inv = 1.0f / lsum;          // valid for q = c15 on every quad-lane

    // --- epilogue: O^T lane holds O[d=16jd+4quad+r][q=c15] ---
    size_t orow = (size_t)batch * N_ + n0 + w * 16 + c15;
    float* op = out + orow * D_ + colOff + quad * 4;
    #pragma unroll
    for (int jd = 0; jd < 4; jd++) {
        #pragma unroll
        for (int r = 0; r < 4; r++) {
            float v = o_acc[jd][r] * inv;
            int col = 16 * jd + r;
            if (accumulate) op[col] += v;
            else            op[col] = v;
        }
    }
}

// ---------------------------------------------------------------------------
extern "C" void kernel_launch(void* const* d_in, const int* in_sizes, int n_in,
                              void* d_out, int out_size, void* d_ws, size_t ws_size,
                              hipStream_t stream) {
    const float* x  = (const float*)d_in[0];
    const float* wq = (const float*)d_in[1];
    const float* bq = (const float*)d_in[2];
    const float* wk = (const float*)d_in[3];
    const float* bk = (const float*)d_in[4];
    const float* wv = (const float*)d_in[5];
    const float* bv = (const float*)d_in[6];
    float* out = (float*)d_out;

    // workspace layout (~61 MB total)
    char* ws = (char*)d_ws;
    bf16*  xbf = (bf16*)ws;                                   // 12,582,912 B
    bf16*  wbf = (bf16*)(ws + 12582912);                      // 10,616,832 B
    float* sc  = (float*)(ws + 12582912 + 10616832);          //     65,536 B
    bf16*  qkv = (bf16*)(ws + 12582912 + 10616832 + 65536);   // 37,748,736 B (one branch's q,k,v)

    hipLaunchKernelGGL(prep_x, dim3(M_), dim3(256), 0, stream, x, xbf, sc);
    hipLaunchKernelGGL(prep_w, dim3((9 * WSZ_ / 4) / 256), dim3(256), 0, stream, wq, wk, wv, wbf);
    for (int br = 0; br < 3; br++) {
        hipLaunchKernelGGL(gemm_qkv, dim3(D_ / BN, M_ / BM, 3), dim3(256), 0, stream,
                           xbf, wbf, bq, bk, bv, sc, br, qkv);
        hipLaunchKernelGGL(attn, dim3(N_ / 64, B_ * H_), dim3(256), 0, stream,
                           qkv, out, br);
    }
}

// Round 5
// 617.745 us; speedup vs baseline: 1.4680x; 1.1260x over previous
//
#include <hip/hip_runtime.h>
#include <hip/hip_bf16.h>
#include <cstdint>
#include <cstddef>

// Problem shape (fixed by reference): B=8, N=1024, D=768, H=12, dh=64, 3 branches
#define B_   8
#define N_   1024
#define D_   768
#define H_   12
#define DH_  64
#define M_   (B_ * N_)          // 8192 rows
#define WSZ_ (D_ * D_)          // 589824 per weight matrix

typedef __bf16 bf16;
typedef bf16  bf16x8  __attribute__((ext_vector_type(8)));
typedef bf16  bf16x4  __attribute__((ext_vector_type(4)));
typedef float floatx4 __attribute__((ext_vector_type(4)));

// ---------------------------------------------------------------------------
// async global->LDS, 16B per lane (wave-uniform LDS base + lane*16)
__device__ __forceinline__ void gload_lds16(const void* g, void* l) {
    __builtin_amdgcn_global_load_lds(
        (const __attribute__((address_space(1))) unsigned int*)g,
        (__attribute__((address_space(3))) unsigned int*)l, 16, 0, 0);
}

// ---------------------------------------------------------------------------
// Kernel 1: per-row norm -> branch scales; x -> bf16.
__global__ __launch_bounds__(256) void prep_x(const float* __restrict__ x,
                                              bf16* __restrict__ xbf,
                                              float* __restrict__ sc /* [2][M_] */) {
    int row = blockIdx.x;
    int tid = threadIdx.x;
    const float* xr = x + (size_t)row * D_;
    bf16* xo = xbf + (size_t)row * D_;
    float v0 = xr[tid], v1 = xr[tid + 256], v2 = xr[tid + 512];
    xo[tid]       = (bf16)v0;
    xo[tid + 256] = (bf16)v1;
    xo[tid + 512] = (bf16)v2;
    float ss = v0 * v0 + v1 * v1 + v2 * v2;
    for (int off = 32; off; off >>= 1) ss += __shfl_xor(ss, off, 64);
    __shared__ float red[4];
    if ((tid & 63) == 0) red[tid >> 6] = ss;
    __syncthreads();
    if (tid == 0) {
        float t2 = red[0] + red[1] + red[2] + red[3];
        float t  = sqrtf(t2);                       // true ||x||
        const float scst = 0.31622776601683794f;    // sqrt(0.1)
        float un = fmaxf(t, 1e-5f);
        float s1 = tanhf(scst * un) / (scst * un);  // expmap0 scale
        float nh = fmaxf(t * s1, 1e-5f);            // project
        float maxnorm = (1.0f - 4e-3f) / scst;
        float sh = (nh > maxnorm) ? s1 * (maxnorm / nh) : s1;
        float arg = fminf(scst * un, 1.0f - 1e-5f); // logmap0 scale
        float artanh = 0.5f * logf((1.0f + arg) / (1.0f - arg));
        float ssc = artanh / (un * scst);
        sc[row]      = sh;
        sc[M_ + row] = ssc;
    }
}

// ---------------------------------------------------------------------------
// Kernel 2: weights fp32 -> bf16, layout wbf[branch][t][o][k], t: 0=q,1=k,2=v
__global__ __launch_bounds__(256) void prep_w(const float* __restrict__ wq,
                                              const float* __restrict__ wk,
                                              const float* __restrict__ wv,
                                              bf16* __restrict__ wbf) {
    size_t i = ((size_t)blockIdx.x * 256 + threadIdx.x) * 4;  // 9*WSZ_ total
    int z = (int)(i / WSZ_);
    int r = (int)(i % WSZ_);
    int branch = z / 3, t = z % 3;
    const float* src = (t == 0 ? wq : t == 1 ? wk : wv) + (size_t)branch * WSZ_ + r;
    float4 f = *(const float4*)src;
    bf16x4 o = { (bf16)f.x, (bf16)f.y, (bf16)f.z, (bf16)f.w };
    *(bf16x4*)(wbf + i) = o;
}

// ---------------------------------------------------------------------------
// Kernel 3: Y = x @ W^T, epilogue y = (s_branch[row]*y + bias[col]) * qscale
// q (t==0) additionally scaled by log2(e) so attention softmax can use exp2.
// blockIdx.z in [0, 3*nb): branch = branchArg + z/3, t = z%3.
#define BM 128
#define BN 128
#define BK 32
__global__ __launch_bounds__(256) void gemm_qkv(
        const bf16* __restrict__ xbf, const bf16* __restrict__ wbf_all,
        const float* __restrict__ bq, const float* __restrict__ bk,
        const float* __restrict__ bv, const float* __restrict__ sc,
        int branchArg, bf16* __restrict__ qkvDst) {
    int zloc = blockIdx.z / 3;
    int branch = branchArg + zloc;
    int t = blockIdx.z % 3;
    const bf16*  wsrc = wbf_all + (size_t)(branch * 3 + t) * WSZ_;
    const float* bias = (t == 0 ? bq : t == 1 ? bk : bv) + branch * D_;
    bf16* out = qkvDst + (size_t)zloc * 3 * M_ * D_ + (size_t)t * M_ * D_;
    int bm0 = blockIdx.y * BM;
    int bn0 = blockIdx.x * BN;

    __shared__ bf16 lA[BM * BK];   // 8 KB
    __shared__ bf16 lB[BN * BK];   // 8 KB

    int tid = threadIdx.x;
    int w = tid >> 6, lane = tid & 63;
    int wr = w >> 1, wc = w & 1;
    int quad = lane >> 4, c15 = lane & 15;
    int lrow = lane >> 2;           // 0..15 within a 16-row chunk
    int lcol = (lane & 3) * 8;      // k offset 0/8/16/24

    floatx4 acc[4][4];
    for (int i = 0; i < 4; i++)
        for (int j = 0; j < 4; j++)
            acc[i][j] = (floatx4){0.f, 0.f, 0.f, 0.f};

    for (int k0 = 0; k0 < D_; k0 += BK) {
        const bf16* ga = xbf  + ((size_t)(bm0 + w * 32 + lrow) * D_ + k0 + lcol);
        const bf16* gb = wsrc + ((size_t)(bn0 + w * 32 + lrow) * D_ + k0 + lcol);
        gload_lds16(ga,           (char*)lA + w * 2048);
        gload_lds16(ga + 16 * D_, (char*)lA + w * 2048 + 1024);
        gload_lds16(gb,           (char*)lB + w * 2048);
        gload_lds16(gb + 16 * D_, (char*)lB + w * 2048 + 1024);
        __syncthreads();

        int arow = wr * 64 + c15;
        int brow = wc * 64 + c15;
        int kq = quad * 8;
        bf16x8 af[4], bfm[4];
        for (int i = 0; i < 4; i++) af[i]  = *(const bf16x8*)(lA + (arow + i * 16) * BK + kq);
        for (int j = 0; j < 4; j++) bfm[j] = *(const bf16x8*)(lB + (brow + j * 16) * BK + kq);
        for (int i = 0; i < 4; i++)
            for (int j = 0; j < 4; j++)
                acc[i][j] = __builtin_amdgcn_mfma_f32_16x16x32_bf16(af[i], bfm[j], acc[i][j], 0, 0, 0);
        __syncthreads();
    }

    // epilogue: y = (s[row]*y + bias[col]) * qs
    const float* scb = (branch == 0) ? nullptr : sc + (size_t)(branch - 1) * M_;
    float qs = (t == 0) ? 1.4426950408889634f : 1.0f;   // log2(e) folded into q
    float bj[4];
    for (int j = 0; j < 4; j++) bj[j] = bias[bn0 + wc * 64 + j * 16 + c15];
    for (int i = 0; i < 4; i++) {
        int gRow0 = bm0 + wr * 64 + i * 16 + quad * 4;
        for (int r = 0; r < 4; r++) {
            float s = scb ? scb[gRow0 + r] : 1.0f;
            bf16* orow = out + (size_t)(gRow0 + r) * D_;
            for (int j = 0; j < 4; j++) {
                int gCol = bn0 + wc * 64 + j * 16 + c15;
                orow[gCol] = (bf16)((s * acc[i][j][r] + bj[j]) * qs);
            }
        }
    }
}

// ---------------------------------------------------------------------------
// Kernel 4: transposed-S flash attention, software-pipelined.
//   S^T = K·Q^T (A=K direct from global in operand layout, no sK LDS).
//   Pipeline: V prefetched right after the barrier (in flight through
//   S+softmax+PV), K prefetched right after its MFMAs consume it (in flight
//   through softmax+PV+next stage). Single barrier per iteration with
//   double-buffered sVt (write buf p / read buf p separated by the barrier;
//   reuse of p two iterations later is protected by the intervening barrier).
//   Grid is bh-major: the 16 q-tiles sharing one (batch,head)'s K/V have
//   linear-id stride 96 == 0 (mod 8) -> same XCD -> K/V L2-local (R3: FETCH
//   dropped to the ideal 37.8 MB with this layout).
#define LDV 72   // rows 144 B: 16B-aligned so b128 LDS reads stay b128
__global__ __launch_bounds__(256) void attn(const bf16* __restrict__ qkvBase,
                                            size_t qkvStride, float* __restrict__ outBase,
                                            size_t outStride, int accumulate) {
    int bh = blockIdx.x;              // 0..95  (same-bh blocks -> same XCD)
    int qt = blockIdx.y;              // 0..15
    int batch = bh / H_, head = bh % H_;
    int n0 = qt * 64;
    int tid = threadIdx.x, w = tid >> 6, lane = tid & 63;
    int quad = lane >> 4, c15 = lane & 15;

    const bf16* qkv = qkvBase + (size_t)blockIdx.z * qkvStride;
    float* outp = outBase + (size_t)blockIdx.z * outStride;
    const bf16* qb = qkv;
    const bf16* kb = qkv + (size_t)M_ * D_;
    const bf16* vg = qkv + (size_t)2 * M_ * D_;
    size_t baseRow = (size_t)batch * N_;
    int colOff = head * DH_;

    __shared__ bf16 sVt[2][64 * LDV];         // 2 x 9216 B
    __shared__ uint32_t sPX[4][2][4][64];     // 8192 B (per-wave private)

    // Q as B-operand frags (16 q-rows per wave), registers for whole kernel
    bf16x8 bq0, bq1;
    {
        const bf16* qp = qb + ((baseRow + n0 + w * 16 + c15) * D_ + colOff + quad * 8);
        bq0 = *(const bf16x8*)qp;
        bq1 = *(const bf16x8*)(qp + 32);
    }

    float lsum = 0.f;                 // in-lane: this lane's 16 keys per iter
    floatx4 o_acc[4];
    for (int j = 0; j < 4; j++) o_acc[j] = (floatx4){0.f, 0.f, 0.f, 0.f};

    // V staging assignment: key-pair kp (keys 2kp,2kp+1), d-block db (8 d's)
    int kp = lane & 31;
    int db = 2 * w + (lane >> 5);
    const bf16* Vg = vg + (baseRow + 2 * kp) * D_ + colOff + db * 8;
    // K A-operand base: row c15 (+16j +64kt), col quad*8
    const bf16* kAbase = kb + (baseRow + c15) * D_ + colOff + quad * 8;

    // prologue: tile 0 into registers
    bf16x8 kA[4][2];
    bf16x8 vr0, vr1;
    #pragma unroll
    for (int j = 0; j < 4; j++) {
        const bf16* kpp = kAbase + (size_t)(16 * j) * D_;
        kA[j][0] = *(const bf16x8*)kpp;
        kA[j][1] = *(const bf16x8*)(kpp + 32);
    }
    vr0 = *(const bf16x8*)Vg;
    vr1 = *(const bf16x8*)(Vg + D_);

    for (int kt = 0; kt < 16; kt++) {
        bf16* sv = sVt[kt & 1];
        int nt = (kt + 1) & 15;       // wraps: last iter's prefetch unused

        // --- stage V (current regs) transposed, key-pair packed u32 writes:
        //     bank = (36d + kp) % 32, kp spans 0..31 -> <=2-way (free) ---
        {
            union { bf16x8 v; uint16_t h[8]; } ua, ub;
            ua.v = vr0; ub.v = vr1;
            #pragma unroll
            for (int i = 0; i < 8; i++) {
                uint32_t wd = (uint32_t)ua.h[i] | ((uint32_t)ub.h[i] << 16);
                *(uint32_t*)((char*)sv + (size_t)((db * 8 + i) * LDV + 2 * kp) * 2) = wd;
            }
        }
        __syncthreads();

        // --- prefetch next V (in flight until next iteration's stage) ---
        {
            const bf16* vp = Vg + (size_t)nt * 64 * D_;
            vr0 = *(const bf16x8*)vp;
            vr1 = *(const bf16x8*)(vp + D_);
        }

        // --- S^T = K Q^T ---
        floatx4 zs[4];
        #pragma unroll
        for (int j = 0; j < 4; j++) {
            floatx4 z = (floatx4){0.f, 0.f, 0.f, 0.f};
            z = __builtin_amdgcn_mfma_f32_16x16x32_bf16(kA[j][0], bq0, z, 0, 0, 0);
            zs[j] = __builtin_amdgcn_mfma_f32_16x16x32_bf16(kA[j][1], bq1, z, 0, 0, 0);
        }
        // --- prefetch next K into the same regs (consumed next iteration) ---
        #pragma unroll
        for (int j = 0; j < 4; j++) {
            const bf16* kpp = kAbase + (size_t)(nt * 64 + 16 * j) * D_;
            kA[j][0] = *(const bf16x8*)kpp;
            kA[j][1] = *(const bf16x8*)(kpp + 32);
        }

        // --- no-max exp2 softmax, pack P pairs ---
        uint32_t pw[4][2];
        #pragma unroll
        for (int j = 0; j < 4; j++) {
            union { bf16 b[2]; uint32_t u; } p01, p23;
            float e0 = __builtin_amdgcn_exp2f(fminf(zs[j][0], 120.f));
            float e1 = __builtin_amdgcn_exp2f(fminf(zs[j][1], 120.f));
            float e2 = __builtin_amdgcn_exp2f(fminf(zs[j][2], 120.f));
            float e3 = __builtin_amdgcn_exp2f(fminf(zs[j][3], 120.f));
            lsum += (e0 + e1) + (e2 + e3);
            p01.b[0] = (bf16)e0; p01.b[1] = (bf16)e1;
            p23.b[0] = (bf16)e2; p23.b[1] = (bf16)e3;
            pw[j][0] = p01.u;
            pw[j][1] = p23.u;
        }
        // scatter P pairs to exchange array (wave-private, no barrier needed)
        {
            int u0 = (quad & 1) * 2;
            #pragma unroll
            for (int j = 0; j < 4; j++) {
                int L = (2 * (j & 1) + (quad >> 1)) * 16 + c15;
                sPX[w][j >> 1][u0][L]     = pw[j][0];
                sPX[w][j >> 1][u0 + 1][L] = pw[j][1];
            }
        }
        // gather B-operand P frags
        union { uint32_t g[4]; bf16x8 v; } pf0, pf1;
        #pragma unroll
        for (int u = 0; u < 4; u++) pf0.g[u] = sPX[w][0][u][lane];
        #pragma unroll
        for (int u = 0; u < 4; u++) pf1.g[u] = sPX[w][1][u][lane];

        // --- O^T += V^T P^T ---
        #pragma unroll
        for (int jd = 0; jd < 4; jd++) {
            const bf16* vt = sv + (16 * jd + c15) * LDV + quad * 8;
            bf16x8 a0 = *(const bf16x8*)vt;
            bf16x8 a1 = *(const bf16x8*)(vt + 32);
            o_acc[jd] = __builtin_amdgcn_mfma_f32_16x16x32_bf16(a0, pf0.v, o_acc[jd], 0, 0, 0);
            o_acc[jd] = __builtin_amdgcn_mfma_f32_16x16x32_bf16(a1, pf1.v, o_acc[jd], 0, 0, 0);
        }
        // no trailing barrier: next iter writes the OTHER sVt buffer; reuse of
        // this buffer (kt+2) is separated from these reads by barrier kt+1.
    }

    // --- final l reduction across quads (disjoint key ranges) ---
    lsum += __shfl_xor(lsum, 16, 64);
    lsum += __shfl_xor(lsum, 32, 64);
    float inv = 1.0f / lsum;          // valid for q = c15 on every quad-lane

    // --- epilogue: O^T lane holds O[d=16jd+4quad+r][q=c15] ---
    size_t orow = (size_t)batch * N_ + n0 + w * 16 + c15;
    float* op = outp + orow * D_ + colOff + quad * 4;
    #pragma unroll
    for (int jd = 0; jd < 4; jd++) {
        #pragma unroll
        for (int r = 0; r < 4; r++) {
            float v = o_acc[jd][r] * inv;
            int col = 16 * jd + r;
            if (accumulate) op[col] += v;
            else            op[col] = v;
        }
    }
}

// ---------------------------------------------------------------------------
// Kernel 5: out = b0 + b1 + b2 (merged path only)
__global__ __launch_bounds__(256) void reduce3(const float* __restrict__ a,
                                               float* __restrict__ out) {
    size_t i = ((size_t)blockIdx.x * 256 + threadIdx.x) * 4;
    const size_t S = (size_t)M_ * D_;
    float4 r0 = *(const float4*)(a + i);
    float4 r1 = *(const float4*)(a + S + i);
    float4 r2 = *(const float4*)(a + 2 * S + i);
    float4 o = { r0.x + r1.x + r2.x, r0.y + r1.y + r2.y,
                 r0.z + r1.z + r2.z, r0.w + r1.w + r2.w };
    *(float4*)(out + i) = o;
}

// ---------------------------------------------------------------------------
extern "C" void kernel_launch(void* const* d_in, const int* in_sizes, int n_in,
                              void* d_out, int out_size, void* d_ws, size_t ws_size,
                              hipStream_t stream) {
    const float* x  = (const float*)d_in[0];
    const float* wq = (const float*)d_in[1];
    const float* bq = (const float*)d_in[2];
    const float* wk = (const float*)d_in[3];
    const float* bk = (const float*)d_in[4];
    const float* wv = (const float*)d_in[5];
    const float* bv = (const float*)d_in[6];
    float* out = (float*)d_out;

    const size_t XBF  = 12582912;   // x bf16
    const size_t WBF  = 10616832;   // 9 weight mats bf16
    const size_t SCZ  = 65536;      // 2*M_ scales
    const size_t QKV1 = 37748736;   // one branch's q,k,v bf16
    const size_t OUT1 = 25165824;   // one branch's fp32 out

    char* ws = (char*)d_ws;
    bf16*  xbf = (bf16*)ws;
    bf16*  wbf = (bf16*)(ws + XBF);
    float* sc  = (float*)(ws + XBF + WBF);
    char*  rest = ws + XBF + WBF + SCZ;
    bool merged = ws_size >= (XBF + WBF + SCZ + 3 * QKV1 + 3 * OUT1);  // 212 MB

    hipLaunchKernelGGL(prep_x, dim3(M_), dim3(256), 0, stream, x, xbf, sc);
    hipLaunchKernelGGL(prep_w, dim3((9 * WSZ_ / 4) / 256), dim3(256), 0, stream, wq, wk, wv, wbf);
    if (merged) {
        bf16*  qkv_all = (bf16*)rest;
        float* out3    = (float*)(rest + 3 * QKV1);
        hipLaunchKernelGGL(gemm_qkv, dim3(D_ / BN, M_ / BM, 9), dim3(256), 0, stream,
                           xbf, wbf, bq, bk, bv, sc, 0, qkv_all);
        hipLaunchKernelGGL(attn, dim3(B_ * H_, N_ / 64, 3), dim3(256), 0, stream,
                           qkv_all, (size_t)3 * M_ * D_, out3, (size_t)M_ * D_, 0);
        hipLaunchKernelGGL(reduce3, dim3((M_ * D_ / 4) / 256), dim3(256), 0, stream,
                           out3, out);
    } else {
        bf16* qkv = (bf16*)rest;
        for (int br = 0; br < 3; br++) {
            hipLaunchKernelGGL(gemm_qkv, dim3(D_ / BN, M_ / BM, 3), dim3(256), 0, stream,
                               xbf, wbf, bq, bk, bv, sc, br, qkv);
            hipLaunchKernelGGL(attn, dim3(B_ * H_, N_ / 64, 1), dim3(256), 0, stream,
                               qkv, (size_t)0, out, (size_t)0, br);
        }
    }
}

// Round 6
// 612.529 us; speedup vs baseline: 1.4805x; 1.0085x over previous
//
#include <hip/hip_runtime.h>
#include <hip/hip_bf16.h>
#include <cstdint>
#include <cstddef>

// Problem shape (fixed by reference): B=8, N=1024, D=768, H=12, dh=64, 3 branches
#define B_   8
#define N_   1024
#define D_   768
#define H_   12
#define DH_  64
#define M_   (B_ * N_)          // 8192 rows
#define WSZ_ (D_ * D_)          // 589824 per weight matrix

typedef __bf16 bf16;
typedef bf16  bf16x8  __attribute__((ext_vector_type(8)));
typedef bf16  bf16x4  __attribute__((ext_vector_type(4)));
typedef float floatx4 __attribute__((ext_vector_type(4)));

// ---------------------------------------------------------------------------
// async global->LDS, 16B per lane (wave-uniform LDS base + lane*16)
__device__ __forceinline__ void gload_lds16(const void* g, void* l) {
    __builtin_amdgcn_global_load_lds(
        (const __attribute__((address_space(1))) unsigned int*)g,
        (__attribute__((address_space(3))) unsigned int*)l, 16, 0, 0);
}

// ---------------------------------------------------------------------------
// Kernel 1: per-row norm -> branch scales; x -> bf16.
__global__ __launch_bounds__(256) void prep_x(const float* __restrict__ x,
                                              bf16* __restrict__ xbf,
                                              float* __restrict__ sc /* [2][M_] */) {
    int row = blockIdx.x;
    int tid = threadIdx.x;
    const float* xr = x + (size_t)row * D_;
    bf16* xo = xbf + (size_t)row * D_;
    float v0 = xr[tid], v1 = xr[tid + 256], v2 = xr[tid + 512];
    xo[tid]       = (bf16)v0;
    xo[tid + 256] = (bf16)v1;
    xo[tid + 512] = (bf16)v2;
    float ss = v0 * v0 + v1 * v1 + v2 * v2;
    for (int off = 32; off; off >>= 1) ss += __shfl_xor(ss, off, 64);
    __shared__ float red[4];
    if ((tid & 63) == 0) red[tid >> 6] = ss;
    __syncthreads();
    if (tid == 0) {
        float t2 = red[0] + red[1] + red[2] + red[3];
        float t  = sqrtf(t2);                       // true ||x||
        const float scst = 0.31622776601683794f;    // sqrt(0.1)
        float un = fmaxf(t, 1e-5f);
        float s1 = tanhf(scst * un) / (scst * un);  // expmap0 scale
        float nh = fmaxf(t * s1, 1e-5f);            // project
        float maxnorm = (1.0f - 4e-3f) / scst;
        float sh = (nh > maxnorm) ? s1 * (maxnorm / nh) : s1;
        float arg = fminf(scst * un, 1.0f - 1e-5f); // logmap0 scale
        float artanh = 0.5f * logf((1.0f + arg) / (1.0f - arg));
        float ssc = artanh / (un * scst);
        sc[row]      = sh;
        sc[M_ + row] = ssc;
    }
}

// ---------------------------------------------------------------------------
// Kernel 2: weights fp32 -> bf16, layout wbf[branch][t][o][k], t: 0=q,1=k,2=v
__global__ __launch_bounds__(256) void prep_w(const float* __restrict__ wq,
                                              const float* __restrict__ wk,
                                              const float* __restrict__ wv,
                                              bf16* __restrict__ wbf) {
    size_t i = ((size_t)blockIdx.x * 256 + threadIdx.x) * 4;  // 9*WSZ_ total
    int z = (int)(i / WSZ_);
    int r = (int)(i % WSZ_);
    int branch = z / 3, t = z % 3;
    const float* src = (t == 0 ? wq : t == 1 ? wk : wv) + (size_t)branch * WSZ_ + r;
    float4 f = *(const float4*)src;
    bf16x4 o = { (bf16)f.x, (bf16)f.y, (bf16)f.z, (bf16)f.w };
    *(bf16x4*)(wbf + i) = o;
}

// ---------------------------------------------------------------------------
// Kernel 3: Y = x @ W^T, epilogue y = (s_branch[row]*y + bias[col]) * qscale
// q (t==0) additionally scaled by log2(e) so attention softmax can use exp2.
// blockIdx.z in [0, 3*nb): branch = branchArg + z/3, t = z%3.
#define BM 128
#define BN 128
#define BK 32
__global__ __launch_bounds__(256) void gemm_qkv(
        const bf16* __restrict__ xbf, const bf16* __restrict__ wbf_all,
        const float* __restrict__ bq, const float* __restrict__ bk,
        const float* __restrict__ bv, const float* __restrict__ sc,
        int branchArg, bf16* __restrict__ qkvDst) {
    int zloc = blockIdx.z / 3;
    int branch = branchArg + zloc;
    int t = blockIdx.z % 3;
    const bf16*  wsrc = wbf_all + (size_t)(branch * 3 + t) * WSZ_;
    const float* bias = (t == 0 ? bq : t == 1 ? bk : bv) + branch * D_;
    bf16* out = qkvDst + (size_t)zloc * 3 * M_ * D_ + (size_t)t * M_ * D_;
    int bm0 = blockIdx.y * BM;
    int bn0 = blockIdx.x * BN;

    __shared__ bf16 lA[BM * BK];   // 8 KB
    __shared__ bf16 lB[BN * BK];   // 8 KB

    int tid = threadIdx.x;
    int w = tid >> 6, lane = tid & 63;
    int wr = w >> 1, wc = w & 1;
    int quad = lane >> 4, c15 = lane & 15;
    int lrow = lane >> 2;           // 0..15 within a 16-row chunk
    int lcol = (lane & 3) * 8;      // k offset 0/8/16/24

    floatx4 acc[4][4];
    for (int i = 0; i < 4; i++)
        for (int j = 0; j < 4; j++)
            acc[i][j] = (floatx4){0.f, 0.f, 0.f, 0.f};

    for (int k0 = 0; k0 < D_; k0 += BK) {
        const bf16* ga = xbf  + ((size_t)(bm0 + w * 32 + lrow) * D_ + k0 + lcol);
        const bf16* gb = wsrc + ((size_t)(bn0 + w * 32 + lrow) * D_ + k0 + lcol);
        gload_lds16(ga,           (char*)lA + w * 2048);
        gload_lds16(ga + 16 * D_, (char*)lA + w * 2048 + 1024);
        gload_lds16(gb,           (char*)lB + w * 2048);
        gload_lds16(gb + 16 * D_, (char*)lB + w * 2048 + 1024);
        __syncthreads();

        int arow = wr * 64 + c15;
        int brow = wc * 64 + c15;
        int kq = quad * 8;
        bf16x8 af[4], bfm[4];
        for (int i = 0; i < 4; i++) af[i]  = *(const bf16x8*)(lA + (arow + i * 16) * BK + kq);
        for (int j = 0; j < 4; j++) bfm[j] = *(const bf16x8*)(lB + (brow + j * 16) * BK + kq);
        for (int i = 0; i < 4; i++)
            for (int j = 0; j < 4; j++)
                acc[i][j] = __builtin_amdgcn_mfma_f32_16x16x32_bf16(af[i], bfm[j], acc[i][j], 0, 0, 0);
        __syncthreads();
    }

    // epilogue: y = (s[row]*y + bias[col]) * qs
    const float* scb = (branch == 0) ? nullptr : sc + (size_t)(branch - 1) * M_;
    float qs = (t == 0) ? 1.4426950408889634f : 1.0f;   // log2(e) folded into q
    float bj[4];
    for (int j = 0; j < 4; j++) bj[j] = bias[bn0 + wc * 64 + j * 16 + c15];
    for (int i = 0; i < 4; i++) {
        int gRow0 = bm0 + wr * 64 + i * 16 + quad * 4;
        for (int r = 0; r < 4; r++) {
            float s = scb ? scb[gRow0 + r] : 1.0f;
            bf16* orow = out + (size_t)(gRow0 + r) * D_;
            for (int j = 0; j < 4; j++) {
                int gCol = bn0 + wc * 64 + j * 16 + c15;
                orow[gCol] = (bf16)((s * acc[i][j][r] + bj[j]) * qs);
            }
        }
    }
}

// ---------------------------------------------------------------------------
// Kernel 4: transposed-S flash attention with ZERO-COST P hand-off.
//
//   S^T = K·Q^T via mfma(A=K, B=Q): lane (quad,c15) of S^T frag j holds
//   P^T[key=16j+4*quad+r][q=c15], r=0..3.
//
//   KEY-ORDER TRICK: PV sums over keys, so key order is arbitrary as long as
//   P-frags and V^T-frags agree. Choose storage order
//        col(key) = 32*(j>>1) + 8*q + 4*(j&1) + r   (key = 16j + 4q + r)
//   Then the PV B-operand frag for k-block 0 is exactly
//        { pw[0][0], pw[0][1], pw[1][0], pw[1][1] }   (this lane's own regs!)
//   and k-block 1 is { pw[2][0], pw[2][1], pw[3][0], pw[3][1] }.
//   P goes MFMA->exp2->pack->MFMA entirely in-register: no LDS, no shuffles.
//   V^T is simply STORED in col(key) order (staging writes remain
//   conflict-free per quarter-wave phase: bank = (4i + bitperm(kp)) % 32).
#define LDV 72   // rows 144 B: 16B-aligned so b128 LDS reads stay b128
__global__ __launch_bounds__(256) void attn(const bf16* __restrict__ qkvBase,
                                            size_t qkvStride, float* __restrict__ outBase,
                                            size_t outStride, int accumulate) {
    int bh = blockIdx.x;              // 0..95  (same-bh blocks -> same XCD)
    int qt = blockIdx.y;              // 0..15
    int batch = bh / H_, head = bh % H_;
    int n0 = qt * 64;
    int tid = threadIdx.x, w = tid >> 6, lane = tid & 63;
    int quad = lane >> 4, c15 = lane & 15;

    const bf16* qkv = qkvBase + (size_t)blockIdx.z * qkvStride;
    float* outp = outBase + (size_t)blockIdx.z * outStride;
    const bf16* qb = qkv;
    const bf16* kb = qkv + (size_t)M_ * D_;
    const bf16* vg = qkv + (size_t)2 * M_ * D_;
    size_t baseRow = (size_t)batch * N_;
    int colOff = head * DH_;

    __shared__ bf16 sVt[2][64 * LDV];         // 2 x 9216 B = 18.4 KB total

    // Q as B-operand frags (16 q-rows per wave), registers for whole kernel
    bf16x8 bq0, bq1;
    {
        const bf16* qp = qb + ((baseRow + n0 + w * 16 + c15) * D_ + colOff + quad * 8);
        bq0 = *(const bf16x8*)qp;
        bq1 = *(const bf16x8*)(qp + 32);
    }

    float lsum = 0.f;                 // in-lane: this lane's 16 keys per iter
    floatx4 o_acc[4];
    for (int j = 0; j < 4; j++) o_acc[j] = (floatx4){0.f, 0.f, 0.f, 0.f};

    // V staging: lane owns key-pair (2kp, 2kp+1), d-block db*8..+7.
    // Destination column (permuted key order), key0 = 2kp:
    //   col0 = 32*(kp>>4) + 8*((kp>>1)&3) + 4*((kp>>3)&1) + 2*(kp&1)
    // col(2kp+1) = col0+1 (r differs by 1, same q,j) -> one u32 write.
    int kp = lane & 31;
    int db = 2 * w + (lane >> 5);
    int vcol0 = 32 * (kp >> 4) + 8 * ((kp >> 1) & 3) + 4 * ((kp >> 3) & 1) + 2 * (kp & 1);
    const bf16* Vg = vg + (baseRow + 2 * kp) * D_ + colOff + db * 8;
    // K A-operand base: row c15 (+16j +64kt), col quad*8
    const bf16* kAbase = kb + (baseRow + c15) * D_ + colOff + quad * 8;

    // prologue: tile 0 into registers
    bf16x8 kA[4][2];
    bf16x8 vr0, vr1;
    #pragma unroll
    for (int j = 0; j < 4; j++) {
        const bf16* kpp = kAbase + (size_t)(16 * j) * D_;
        kA[j][0] = *(const bf16x8*)kpp;
        kA[j][1] = *(const bf16x8*)(kpp + 32);
    }
    vr0 = *(const bf16x8*)Vg;
    vr1 = *(const bf16x8*)(Vg + D_);

    for (int kt = 0; kt < 16; kt++) {
        bf16* sv = sVt[kt & 1];
        int nt = (kt + 1) & 15;       // wraps: last iter's prefetch unused

        // --- stage V (current regs), permuted-key-order packed u32 writes ---
        {
            union { bf16x8 v; uint16_t h[8]; } ua, ub;
            ua.v = vr0; ub.v = vr1;
            #pragma unroll
            for (int i = 0; i < 8; i++) {
                uint32_t wd = (uint32_t)ua.h[i] | ((uint32_t)ub.h[i] << 16);
                *(uint32_t*)((char*)sv + (size_t)((db * 8 + i) * LDV + vcol0) * 2) = wd;
            }
        }
        __syncthreads();

        // --- prefetch next V (in flight until next iteration's stage) ---
        {
            const bf16* vp = Vg + (size_t)nt * 64 * D_;
            vr0 = *(const bf16x8*)vp;
            vr1 = *(const bf16x8*)(vp + D_);
        }

        // --- S^T = K Q^T ---
        floatx4 zs[4];
        #pragma unroll
        for (int j = 0; j < 4; j++) {
            floatx4 z = (floatx4){0.f, 0.f, 0.f, 0.f};
            z = __builtin_amdgcn_mfma_f32_16x16x32_bf16(kA[j][0], bq0, z, 0, 0, 0);
            zs[j] = __builtin_amdgcn_mfma_f32_16x16x32_bf16(kA[j][1], bq1, z, 0, 0, 0);
        }
        // --- prefetch next K (consumed next iteration) ---
        #pragma unroll
        for (int j = 0; j < 4; j++) {
            const bf16* kpp = kAbase + (size_t)(nt * 64 + 16 * j) * D_;
            kA[j][0] = *(const bf16x8*)kpp;
            kA[j][1] = *(const bf16x8*)(kpp + 32);
        }

        // --- no-max exp2 softmax; pack P pairs (in-register B-frags) ---
        uint32_t pw[4][2];
        #pragma unroll
        for (int j = 0; j < 4; j++) {
            union { bf16 b[2]; uint32_t u; } p01, p23;
            float e0 = __builtin_amdgcn_exp2f(fminf(zs[j][0], 120.f));
            float e1 = __builtin_amdgcn_exp2f(fminf(zs[j][1], 120.f));
            float e2 = __builtin_amdgcn_exp2f(fminf(zs[j][2], 120.f));
            float e3 = __builtin_amdgcn_exp2f(fminf(zs[j][3], 120.f));
            lsum += (e0 + e1) + (e2 + e3);
            p01.b[0] = (bf16)e0; p01.b[1] = (bf16)e1;
            p23.b[0] = (bf16)e2; p23.b[1] = (bf16)e3;
            pw[j][0] = p01.u;
            pw[j][1] = p23.u;
        }
        union { uint32_t g[4]; bf16x8 v; } pf0, pf1;
        pf0.g[0] = pw[0][0]; pf0.g[1] = pw[0][1];
        pf0.g[2] = pw[1][0]; pf0.g[3] = pw[1][1];
        pf1.g[0] = pw[2][0]; pf1.g[1] = pw[2][1];
        pf1.g[2] = pw[3][0]; pf1.g[3] = pw[3][1];

        // --- O^T += V^T P^T (A from sVt in matching permuted key order) ---
        #pragma unroll
        for (int jd = 0; jd < 4; jd++) {
            const bf16* vt = sv + (16 * jd + c15) * LDV + quad * 8;
            bf16x8 a0 = *(const bf16x8*)vt;
            bf16x8 a1 = *(const bf16x8*)(vt + 32);
            o_acc[jd] = __builtin_amdgcn_mfma_f32_16x16x32_bf16(a0, pf0.v, o_acc[jd], 0, 0, 0);
            o_acc[jd] = __builtin_amdgcn_mfma_f32_16x16x32_bf16(a1, pf1.v, o_acc[jd], 0, 0, 0);
        }
        // no trailing barrier: next iter writes the OTHER sVt buffer; reuse of
        // this buffer (kt+2) is separated from these reads by barrier kt+1.
    }

    // --- final l reduction across quads (disjoint key ranges) ---
    lsum += __shfl_xor(lsum, 16, 64);
    lsum += __shfl_xor(lsum, 32, 64);
    float inv = 1.0f / lsum;          // valid for q = c15 on every quad-lane

    // --- epilogue: O^T lane holds O[d=16jd+4quad+r][q=c15] ---
    size_t orow = (size_t)batch * N_ + n0 + w * 16 + c15;
    float* op = outp + orow * D_ + colOff + quad * 4;
    #pragma unroll
    for (int jd = 0; jd < 4; jd++) {
        #pragma unroll
        for (int r = 0; r < 4; r++) {
            float v = o_acc[jd][r] * inv;
            int col = 16 * jd + r;
            if (accumulate) op[col] += v;
            else            op[col] = v;
        }
    }
}

// ---------------------------------------------------------------------------
// Kernel 5: out = b0 + b1 + b2 (merged path only)
__global__ __launch_bounds__(256) void reduce3(const float* __restrict__ a,
                                               float* __restrict__ out) {
    size_t i = ((size_t)blockIdx.x * 256 + threadIdx.x) * 4;
    const size_t S = (size_t)M_ * D_;
    float4 r0 = *(const float4*)(a + i);
    float4 r1 = *(const float4*)(a + S + i);
    float4 r2 = *(const float4*)(a + 2 * S + i);
    float4 o = { r0.x + r1.x + r2.x, r0.y + r1.y + r2.y,
                 r0.z + r1.z + r2.z, r0.w + r1.w + r2.w };
    *(float4*)(out + i) = o;
}

// ---------------------------------------------------------------------------
extern "C" void kernel_launch(void* const* d_in, const int* in_sizes, int n_in,
                              void* d_out, int out_size, void* d_ws, size_t ws_size,
                              hipStream_t stream) {
    const float* x  = (const float*)d_in[0];
    const float* wq = (const float*)d_in[1];
    const float* bq = (const float*)d_in[2];
    const float* wk = (const float*)d_in[3];
    const float* bk = (const float*)d_in[4];
    const float* wv = (const float*)d_in[5];
    const float* bv = (const float*)d_in[6];
    float* out = (float*)d_out;

    const size_t XBF  = 12582912;   // x bf16
    const size_t WBF  = 10616832;   // 9 weight mats bf16
    const size_t SCZ  = 65536;      // 2*M_ scales
    const size_t QKV1 = 37748736;   // one branch's q,k,v bf16
    const size_t OUT1 = 25165824;   // one branch's fp32 out

    char* ws = (char*)d_ws;
    bf16*  xbf = (bf16*)ws;
    bf16*  wbf = (bf16*)(ws + XBF);
    float* sc  = (float*)(ws + XBF + WBF);
    char*  rest = ws + XBF + WBF + SCZ;
    bool merged = ws_size >= (XBF + WBF + SCZ + 3 * QKV1 + 3 * OUT1);  // 212 MB

    hipLaunchKernelGGL(prep_x, dim3(M_), dim3(256), 0, stream, x, xbf, sc);
    hipLaunchKernelGGL(prep_w, dim3((9 * WSZ_ / 4) / 256), dim3(256), 0, stream, wq, wk, wv, wbf);
    if (merged) {
        bf16*  qkv_all = (bf16*)rest;
        float* out3    = (float*)(rest + 3 * QKV1);
        hipLaunchKernelGGL(gemm_qkv, dim3(D_ / BN, M_ / BM, 9), dim3(256), 0, stream,
                           xbf, wbf, bq, bk, bv, sc, 0, qkv_all);
        hipLaunchKernelGGL(attn, dim3(B_ * H_, N_ / 64, 3), dim3(256), 0, stream,
                           qkv_all, (size_t)3 * M_ * D_, out3, (size_t)M_ * D_, 0);
        hipLaunchKernelGGL(reduce3, dim3((M_ * D_ / 4) / 256), dim3(256), 0, stream,
                           out3, out);
    } else {
        bf16* qkv = (bf16*)rest;
        for (int br = 0; br < 3; br++) {
            hipLaunchKernelGGL(gemm_qkv, dim3(D_ / BN, M_ / BM, 3), dim3(256), 0, stream,
                               xbf, wbf, bq, bk, bv, sc, br, qkv);
            hipLaunchKernelGGL(attn, dim3(B_ * H_, N_ / 64, 1), dim3(256), 0, stream,
                               qkv, (size_t)0, out, (size_t)0, br);
        }
    }
}